// Round 5
// baseline (586.902 us; speedup 1.0000x reference)
//
#include <hip/hip_runtime.h>
#include <stdint.h>

// Problem constants (from reference)
#define N_VIEWS 5
#define B_ 8
#define C_ 15
#define CP_ 16               // channel-padded: 16 x fp8 = 16B per pixel
#define H_ 256
#define W_ 480
#define NBINS 128000          // 80*80*20
#define HW_ (H_ * W_)
#define CUBES_ELEMS (B_ * C_ * NBINS)
#define NB_ (N_VIEWS * B_)    // 40 images
#define LDS_RECS 3072         // 48 KB staging buffer -> 3 blocks/CU

typedef float v2f __attribute__((ext_vector_type(2)));

// ---------------------------------------------------------------------------
// Kernel 1: transpose+quantize (N,B,C,H,W) f32 -> (N,B,H,W,16) fp8 e4m3 (OCP)
// XCD-aligned: flat grid, b = bid & 7, matching project's affinity.
// At the HBM floor (~295 MB read + 79 MB write ≈ 58 µs).
// ---------------------------------------------------------------------------
__global__ __launch_bounds__(256) void transpose_fp8_kernel(
    const float* __restrict__ hm, uint32_t* __restrict__ tp)
{
    const int bid  = blockIdx.x;          // 0..19199 (2400 per image-batch)
    const int b    = bid & 7;             // XCD affinity, matches project
    const int rest = bid >> 3;            // 0..2399
    const int n    = rest % 5;
    const int tile = rest / 5;            // 0..479
    const int cb   = n * B_ + b;
    const int idx  = tile * 256 + (int)threadIdx.x;
    if (idx >= HW_) return;
    const float* src = hm + (size_t)cb * C_ * HW_ + idx;
    float v[CP_];
#pragma unroll
    for (int c = 0; c < C_; ++c) v[c] = src[(size_t)c * HW_];
    v[15] = 0.0f;
    uint32_t w[4];
#pragma unroll
    for (int j = 0; j < 4; ++j) {
        int r = 0;
        r = __builtin_amdgcn_cvt_pk_fp8_f32(v[4*j + 0], v[4*j + 1], r, false); // bytes 1:0
        r = __builtin_amdgcn_cvt_pk_fp8_f32(v[4*j + 2], v[4*j + 3], r, true);  // bytes 3:2
        w[j] = (uint32_t)r;
    }
    uint4* dst = (uint4*)(tp + ((size_t)cb * HW_ + (size_t)idx) * 4);
    *dst = make_uint4(w[0], w[1], w[2], w[3]);
}

// ---------------------------------------------------------------------------
// Shared projection math — per-lane branchless; keeps clamped corner indices
// so callers can form LDS-local or global offsets. OOB lanes: weights 0.
// ---------------------------------------------------------------------------
struct Proj { int xi0, yi0, xi1, yi1; float w00, w10, w01, w11, inb; };

__device__ __forceinline__ Proj project_one(
    int cb, float gx, float gy, float gz,
    const float* __restrict__ R, const float* __restrict__ T,
    const float* __restrict__ f, const float* __restrict__ ccam,
    const float* __restrict__ trans, const float* __restrict__ wh)
{
    Proj r;
    const float* Rn = R + cb * 9;
    const float px = gx - T[cb * 3 + 0];
    const float py = gy - T[cb * 3 + 1];
    const float pz = gz - T[cb * 3 + 2];
    const float xcm = Rn[0] * px + Rn[1] * py + Rn[2] * pz;
    const float ycm = Rn[3] * px + Rn[4] * py + Rn[5] * pz;
    const float zcm = Rn[6] * px + Rn[7] * py + Rn[8] * pz;
    const float u = f[cb * 2 + 0] * (xcm / zcm) + ccam[cb * 2 + 0];
    const float v = f[cb * 2 + 1] * (ycm / zcm) + ccam[cb * 2 + 1];
    const float w0 = wh[cb * 2 + 0], w1 = wh[cb * 2 + 1];
    const bool inb = (u >= 0.0f) & (u < w0) & (v >= 0.0f) & (v < w1);
    const float inbf = inb ? 1.0f : 0.0f;
    const float mx = fmaxf(w0, w1);
    const float uu = fminf(fmaxf(u, -1.0f), mx);
    const float vv = fminf(fmaxf(v, -1.0f), mx);
    const float* tr = trans + cb * 6;
    const float tx = (tr[0] * uu + tr[1] * vv + tr[2]) * 0.5f;
    const float ty = (tr[3] * uu + tr[4] * vv + tr[5]) * 0.5f;
    const float sgx = fminf(fmaxf(tx / 479.0f * 2.0f - 1.0f, -1.1f), 1.1f);
    const float sgy = fminf(fmaxf(ty / 255.0f * 2.0f - 1.0f, -1.1f), 1.1f);
    const float ixf = (sgx + 1.0f) * 0.5f * 479.0f;
    const float iyf = (sgy + 1.0f) * 0.5f * 255.0f;
    const float x0 = floorf(ixf), y0 = floorf(iyf);
    const float x1 = x0 + 1.0f, y1 = y0 + 1.0f;
    const float wx1 = ixf - x0, wy1 = iyf - y0;
    const float wx0 = 1.0f - wx1, wy0 = 1.0f - wy1;
    const float v00 = (x0 >= 0.0f && y0 >= 0.0f) ? inbf : 0.0f;
    const float v10 = (x1 <= 479.0f && y0 >= 0.0f) ? inbf : 0.0f;
    const float v01 = (x0 >= 0.0f && y1 <= 255.0f) ? inbf : 0.0f;
    const float v11 = (x1 <= 479.0f && y1 <= 255.0f) ? inbf : 0.0f;
    r.w00 = wx0 * wy0 * v00; r.w10 = wx1 * wy0 * v10;
    r.w01 = wx0 * wy1 * v01; r.w11 = wx1 * wy1 * v11;
    r.xi0 = min(max((int)x0, 0), W_ - 1);
    r.yi0 = min(max((int)y0, 0), H_ - 1);
    r.xi1 = min(max((int)x1, 0), W_ - 1);
    r.yi1 = min(max((int)y1, 0), H_ - 1);
    r.inb = inbf;
    return r;
}

// decode one 16B pixel record (16 fp8) and FMA with weight into acc[16]
__device__ __forceinline__ void acc_pixel(float* acc, uint4 q, float wgt)
{
    const uint32_t u[4] = { q.x, q.y, q.z, q.w };
#pragma unroll
    for (int j = 0; j < 4; ++j) {
        v2f lo = __builtin_amdgcn_cvt_pk_f32_fp8(u[j], false);
        v2f hi = __builtin_amdgcn_cvt_pk_f32_fp8(u[j], true);
        acc[4*j + 0] += wgt * lo.x;
        acc[4*j + 1] += wgt * lo.y;
        acc[4*j + 2] += wgt * hi.x;
        acc[4*j + 3] += wgt * hi.y;
    }
}

// ---------------------------------------------------------------------------
// Kernel 2: LDS-staged bilinear. Theory: TCP pays a per-unique-address cost
// for divergent gathers (grid spacing >> pixel spacing -> every lane-corner
// is its own address; explains R2/R3/R4 nulls). Fix: per view, cooperatively
// stage the block's image bbox into LDS with COALESCED loads, then bilinear
// via ds_read (no per-address TCP cost). Bbox = block-reduced min/max of the
// per-lane clamped corner indices (in-bounds lanes only) -> exact cover ->
// identical records, weights, order -> bit-identical output. Oversized bbox
// (tiles near a camera): fall back to global gathers. Fully-OOB view: skip.
// Tile 8x8x4 (R4), XCD affinity b = bid & 7.
// ---------------------------------------------------------------------------
__global__ __launch_bounds__(256) void project_kernel_fp8(
    const uint32_t* __restrict__ tp,  // (N,B,H,W,16) fp8
    const float* __restrict__ R, const float* __restrict__ T,
    const float* __restrict__ f, const float* __restrict__ ccam,
    const float* __restrict__ trans, const float* __restrict__ wh,
    const float* __restrict__ gc,
    float* __restrict__ out)
{
    __shared__ uint4 s_img[LDS_RECS];     // 48 KB
    __shared__ int   s_red[16];           // cross-wave bbox reduce

    const int bid  = blockIdx.x;           // 0..3999
    const int b    = bid & 7;              // XCD affinity: one b per XCD
    const int tile = bid >> 3;             // 0..499
    const int tz = tile % 5;
    const int ty = (tile / 5) % 10;
    const int tx = tile / 50;
    const int tid = (int)threadIdx.x;
    const int lz = tid & 3;
    const int ly = (tid >> 2) & 7;
    const int lx = tid >> 5;
    const int ixg = tx * 8 + lx;
    const int iyg = ty * 8 + ly;
    const int izg = tz * 4 + lz;
    const int p   = ixg * 1600 + iyg * 20 + izg;

    const float gx = (float)(-4000.0 + ixg * (8000.0 / 79.0)) + gc[b * 3 + 0];
    const float gy = (float)(-4000.0 + iyg * (8000.0 / 79.0)) + gc[b * 3 + 1];
    const float gz = (float)(-1000.0 + izg * (2000.0 / 19.0)) + gc[b * 3 + 2];
    {
        const size_t goff = (size_t)CUBES_ELEMS + ((size_t)b * NBINS + (size_t)p) * 3;
        out[goff + 0] = gx; out[goff + 1] = gy; out[goff + 2] = gz;
    }

    // Phase A: all 5 projections (register-resident, no loads)
    Proj pr[N_VIEWS];
#pragma unroll
    for (int n = 0; n < N_VIEWS; ++n)
        pr[n] = project_one(n * B_ + b, gx, gy, gz, R, T, f, ccam, trans, wh);

    float acc[CP_];
#pragma unroll
    for (int c = 0; c < CP_; ++c) acc[c] = 0.0f;
    float bndsum = 0.0f;

#pragma unroll 1
    for (int n = 0; n < N_VIEWS; ++n) {
        const Proj P = pr[n];
        const bool inb = (P.inb != 0.0f);
        const uint4* base = (const uint4*)tp + (size_t)(n * B_ + b) * HW_;

        // block-wide bbox of clamped corner indices (in-bounds lanes only)
        int mnx = inb ? P.xi0 : 0x7fffffff;
        int mxx = inb ? P.xi1 : (int)0x80000000;
        int mny = inb ? P.yi0 : 0x7fffffff;
        int mxy = inb ? P.yi1 : (int)0x80000000;
#pragma unroll
        for (int o = 32; o > 0; o >>= 1) {
            mnx = min(mnx, __shfl_xor(mnx, o));
            mxx = max(mxx, __shfl_xor(mxx, o));
            mny = min(mny, __shfl_xor(mny, o));
            mxy = max(mxy, __shfl_xor(mxy, o));
        }
        if ((tid & 63) == 0) {
            const int wid = tid >> 6;
            s_red[wid * 4 + 0] = mnx; s_red[wid * 4 + 1] = mxx;
            s_red[wid * 4 + 2] = mny; s_red[wid * 4 + 3] = mxy;
        }
        __syncthreads();
        mnx = s_red[0]; mxx = s_red[1]; mny = s_red[2]; mxy = s_red[3];
#pragma unroll
        for (int w = 1; w < 4; ++w) {
            mnx = min(mnx, s_red[w * 4 + 0]); mxx = max(mxx, s_red[w * 4 + 1]);
            mny = min(mny, s_red[w * 4 + 2]); mxy = max(mxy, s_red[w * 4 + 3]);
        }
        __syncthreads();   // s_red free for next view; s_img reads of prev view done

        bndsum += P.inb;
        if (mnx > mxx) continue;          // whole block OOB for this view (uniform)

        const int bw = mxx - mnx + 1;
        const int bh = mxy - mny + 1;
        uint4 q00, q10, q01, q11;
        if (bw * bh <= LDS_RECS) {
            // coalesced cooperative stage: rows round-robin over waves
            const int wid = tid >> 6, lane = tid & 63;
            for (int row = wid; row < bh; row += 4) {
                const uint4* srow = base + (size_t)(mny + row) * W_ + mnx;
                uint4* drow = s_img + row * bw;
                for (int col = lane; col < bw; col += 64) drow[col] = srow[col];
            }
            __syncthreads();
            const int l00 = inb ? (P.yi0 - mny) * bw + (P.xi0 - mnx) : 0;
            const int l10 = inb ? (P.yi0 - mny) * bw + (P.xi1 - mnx) : 0;
            const int l01 = inb ? (P.yi1 - mny) * bw + (P.xi0 - mnx) : 0;
            const int l11 = inb ? (P.yi1 - mny) * bw + (P.xi1 - mnx) : 0;
            q00 = s_img[l00]; q10 = s_img[l10];
            q01 = s_img[l01]; q11 = s_img[l11];
            __syncthreads();  // all reads done before next view overwrites
        } else {
            // oversized bbox (tile near a camera): global gather fallback
            q00 = base[inb ? P.yi0 * W_ + P.xi0 : 0];
            q10 = base[inb ? P.yi0 * W_ + P.xi1 : 0];
            q01 = base[inb ? P.yi1 * W_ + P.xi0 : 0];
            q11 = base[inb ? P.yi1 * W_ + P.xi1 : 0];
        }
        acc_pixel(acc, q00, P.w00);
        acc_pixel(acc, q10, P.w10);
        acc_pixel(acc, q01, P.w01);
        acc_pixel(acc, q11, P.w11);
    }

    const float inv = 1.0f / (bndsum + 1e-6f);
    const size_t ob = (size_t)b * C_ * NBINS + (size_t)p;
#pragma unroll
    for (int c = 0; c < C_; ++c) {
        float r = acc[c] * inv;
        r = fmaxf(r, 0.0f);   // nan_to_num + clip low
        r = fminf(r, 1.0f);
        out[ob + (size_t)c * NBINS] = r;
    }
}

// ---------------------------------------------------------------------------
// Fallback: direct f32 gather (used only if ws too small). Exact math.
// ---------------------------------------------------------------------------
__device__ __forceinline__ void decode_grid(int p, int b, const float* __restrict__ gc,
                                            float& gx, float& gy, float& gz)
{
    const int ixg = p / 1600;
    const int rem = p - ixg * 1600;
    const int iyg = rem / 20;
    const int izg = rem - iyg * 20;
    gx = (float)(-4000.0 + ixg * (8000.0 / 79.0)) + gc[b * 3 + 0];
    gy = (float)(-4000.0 + iyg * (8000.0 / 79.0)) + gc[b * 3 + 1];
    gz = (float)(-1000.0 + izg * (2000.0 / 19.0)) + gc[b * 3 + 2];
}

__global__ __launch_bounds__(256) void project_kernel_direct(
    const float* __restrict__ hm,
    const float* __restrict__ R, const float* __restrict__ T,
    const float* __restrict__ f, const float* __restrict__ ccam,
    const float* __restrict__ trans, const float* __restrict__ wh,
    const float* __restrict__ gc,
    float* __restrict__ out)
{
    const int p = blockIdx.x * blockDim.x + threadIdx.x;
    const int b = blockIdx.y;
    if (p >= NBINS) return;
    float gx, gy, gz;
    decode_grid(p, b, gc, gx, gy, gz);
    {
        const size_t goff = (size_t)CUBES_ELEMS + ((size_t)b * NBINS + (size_t)p) * 3;
        out[goff + 0] = gx; out[goff + 1] = gy; out[goff + 2] = gz;
    }
    float acc[C_];
#pragma unroll
    for (int c = 0; c < C_; ++c) acc[c] = 0.0f;
    float bndsum = 0.0f;
#pragma unroll
    for (int n = 0; n < N_VIEWS; ++n) {
        const int cb = n * B_ + b;
        Proj cr = project_one(cb, gx, gy, gz, R, T, f, ccam, trans, wh);
        bndsum += cr.inb;
        const bool inb = (cr.inb != 0.0f);
        const int o00 = inb ? cr.yi0 * W_ + cr.xi0 : 0;
        const int o10 = inb ? cr.yi0 * W_ + cr.xi1 : 0;
        const int o01 = inb ? cr.yi1 * W_ + cr.xi0 : 0;
        const int o11 = inb ? cr.yi1 * W_ + cr.xi1 : 0;
        const float* img = hm + (size_t)cb * C_ * HW_;
#pragma unroll
        for (int c = 0; c < C_; ++c) {
            const float* ic = img + (size_t)c * HW_;
            acc[c] += cr.w00 * ic[o00] + cr.w10 * ic[o10]
                    + cr.w01 * ic[o01] + cr.w11 * ic[o11];
        }
    }
    const float inv = 1.0f / (bndsum + 1e-6f);
    const size_t ob = (size_t)b * C_ * NBINS + (size_t)p;
#pragma unroll
    for (int c = 0; c < C_; ++c) {
        float r = acc[c] * inv;
        r = fmaxf(r, 0.0f);
        r = fminf(r, 1.0f);
        out[ob + (size_t)c * NBINS] = r;
    }
}

extern "C" void kernel_launch(void* const* d_in, const int* in_sizes, int n_in,
                              void* d_out, int out_size, void* d_ws, size_t ws_size,
                              hipStream_t stream) {
    const float* hm    = (const float*)d_in[0];
    const float* R     = (const float*)d_in[1];
    const float* T     = (const float*)d_in[2];
    const float* f     = (const float*)d_in[3];
    const float* ccam  = (const float*)d_in[4];
    const float* trans = (const float*)d_in[5];
    const float* wh    = (const float*)d_in[6];
    const float* gc    = (const float*)d_in[7];
    float* out = (float*)d_out;

    const size_t ws_needed = (size_t)NB_ * HW_ * CP_; // 78.6 MB (fp8 bytes)

    if (ws_size >= ws_needed) {
        uint32_t* tp = (uint32_t*)d_ws;
        dim3 tgrid((HW_ / 256) * NB_);        // 19200 flat, b = bid & 7
        transpose_fp8_kernel<<<tgrid, 256, 0, stream>>>(hm, tp);
        dim3 grid((NBINS / 256) * B_);        // 4000 flat, b = bid & 7
        project_kernel_fp8<<<grid, 256, 0, stream>>>(tp, R, T, f, ccam, trans, wh, gc, out);
    } else {
        dim3 grid(NBINS / 256, B_);
        project_kernel_direct<<<grid, 256, 0, stream>>>(hm, R, T, f, ccam, trans, wh, gc, out);
    }
}

// Round 6
// 489.285 us; speedup vs baseline: 1.1995x; 1.1995x over previous
//
#include <hip/hip_runtime.h>
#include <stdint.h>

// Problem constants (from reference)
#define N_VIEWS 5
#define B_ 8
#define C_ 15
#define CP_ 16               // channel-padded: 16 x fp8 = 16B per pixel
#define H_ 256
#define W_ 480
#define NBINS 128000          // 80*80*20
#define HW_ (H_ * W_)
#define CUBES_ELEMS (B_ * C_ * NBINS)
#define NB_ (N_VIEWS * B_)    // 40 images

typedef float v2f __attribute__((ext_vector_type(2)));

// ---------------------------------------------------------------------------
// Kernel 1: transpose+quantize (N,B,C,H,W) f32 -> (N,B,H,W,16) fp8 e4m3 (OCP)
// XCD-aligned: flat grid, b = bid & 7, matching project's affinity.
// At the HBM floor (~295 MB read + 79 MB write ≈ 58 µs).
// ---------------------------------------------------------------------------
__global__ __launch_bounds__(256) void transpose_fp8_kernel(
    const float* __restrict__ hm, uint32_t* __restrict__ tp)
{
    const int bid  = blockIdx.x;          // 0..19199 (2400 per image-batch)
    const int b    = bid & 7;             // XCD affinity, matches project
    const int rest = bid >> 3;            // 0..2399
    const int n    = rest % 5;
    const int tile = rest / 5;            // 0..479
    const int cb   = n * B_ + b;
    const int idx  = tile * 256 + (int)threadIdx.x;
    if (idx >= HW_) return;
    const float* src = hm + (size_t)cb * C_ * HW_ + idx;
    float v[CP_];
#pragma unroll
    for (int c = 0; c < C_; ++c) v[c] = src[(size_t)c * HW_];
    v[15] = 0.0f;
    uint32_t w[4];
#pragma unroll
    for (int j = 0; j < 4; ++j) {
        int r = 0;
        r = __builtin_amdgcn_cvt_pk_fp8_f32(v[4*j + 0], v[4*j + 1], r, false); // bytes 1:0
        r = __builtin_amdgcn_cvt_pk_fp8_f32(v[4*j + 2], v[4*j + 3], r, true);  // bytes 3:2
        w[j] = (uint32_t)r;
    }
    uint4* dst = (uint4*)(tp + ((size_t)cb * HW_ + (size_t)idx) * 4);
    *dst = make_uint4(w[0], w[1], w[2], w[3]);
}

// ---------------------------------------------------------------------------
// Shared projection math — per-lane branchless; returns clamped corner
// indices + weights. OOB lanes: all four weights 0.
// ---------------------------------------------------------------------------
struct Proj { int xi0, yi0, xi1, yi1; float w00, w10, w01, w11, inb; };

__device__ __forceinline__ Proj project_one(
    int cb, float gx, float gy, float gz,
    const float* __restrict__ R, const float* __restrict__ T,
    const float* __restrict__ f, const float* __restrict__ ccam,
    const float* __restrict__ trans, const float* __restrict__ wh)
{
    Proj r;
    const float* Rn = R + cb * 9;
    const float px = gx - T[cb * 3 + 0];
    const float py = gy - T[cb * 3 + 1];
    const float pz = gz - T[cb * 3 + 2];
    const float xcm = Rn[0] * px + Rn[1] * py + Rn[2] * pz;
    const float ycm = Rn[3] * px + Rn[4] * py + Rn[5] * pz;
    const float zcm = Rn[6] * px + Rn[7] * py + Rn[8] * pz;
    const float u = f[cb * 2 + 0] * (xcm / zcm) + ccam[cb * 2 + 0];
    const float v = f[cb * 2 + 1] * (ycm / zcm) + ccam[cb * 2 + 1];
    const float w0 = wh[cb * 2 + 0], w1 = wh[cb * 2 + 1];
    const bool inb = (u >= 0.0f) & (u < w0) & (v >= 0.0f) & (v < w1);
    const float inbf = inb ? 1.0f : 0.0f;
    const float mx = fmaxf(w0, w1);
    const float uu = fminf(fmaxf(u, -1.0f), mx);
    const float vv = fminf(fmaxf(v, -1.0f), mx);
    const float* tr = trans + cb * 6;
    const float tx = (tr[0] * uu + tr[1] * vv + tr[2]) * 0.5f;
    const float ty = (tr[3] * uu + tr[4] * vv + tr[5]) * 0.5f;
    const float sgx = fminf(fmaxf(tx / 479.0f * 2.0f - 1.0f, -1.1f), 1.1f);
    const float sgy = fminf(fmaxf(ty / 255.0f * 2.0f - 1.0f, -1.1f), 1.1f);
    const float ixf = (sgx + 1.0f) * 0.5f * 479.0f;
    const float iyf = (sgy + 1.0f) * 0.5f * 255.0f;
    const float x0 = floorf(ixf), y0 = floorf(iyf);
    const float x1 = x0 + 1.0f, y1 = y0 + 1.0f;
    const float wx1 = ixf - x0, wy1 = iyf - y0;
    const float wx0 = 1.0f - wx1, wy0 = 1.0f - wy1;
    const float v00 = (x0 >= 0.0f && y0 >= 0.0f) ? inbf : 0.0f;
    const float v10 = (x1 <= 479.0f && y0 >= 0.0f) ? inbf : 0.0f;
    const float v01 = (x0 >= 0.0f && y1 <= 255.0f) ? inbf : 0.0f;
    const float v11 = (x1 <= 479.0f && y1 <= 255.0f) ? inbf : 0.0f;
    r.w00 = wx0 * wy0 * v00; r.w10 = wx1 * wy0 * v10;
    r.w01 = wx0 * wy1 * v01; r.w11 = wx1 * wy1 * v11;
    r.xi0 = min(max((int)x0, 0), W_ - 1);
    r.yi0 = min(max((int)y0, 0), H_ - 1);
    r.xi1 = min(max((int)x1, 0), W_ - 1);
    r.yi1 = min(max((int)y1, 0), H_ - 1);
    r.inb = inbf;
    return r;
}

// decode one 16B pixel record (16 fp8) and FMA with weight into acc[16]
__device__ __forceinline__ void acc_pixel(float* acc, uint4 q, float wgt)
{
    const uint32_t u[4] = { q.x, q.y, q.z, q.w };
#pragma unroll
    for (int j = 0; j < 4; ++j) {
        v2f lo = __builtin_amdgcn_cvt_pk_f32_fp8(u[j], false);
        v2f hi = __builtin_amdgcn_cvt_pk_f32_fp8(u[j], true);
        acc[4*j + 0] += wgt * lo.x;
        acc[4*j + 1] += wgt * lo.y;
        acc[4*j + 2] += wgt * hi.x;
        acc[4*j + 3] += wgt * hi.y;
    }
}

// ---------------------------------------------------------------------------
// Kernel 2: VIEW-SERIALIZED software-pipelined gather.
// Theory (from R5 counters: project FETCH=297MB at 1.7TB/s, dur 177µs):
// gathers are HBM/L3-latency bound because issuing all 5 views at once pins
// each XCD's instantaneous working set at 9.8MB (2.5x its 4MB L2) -> misses.
// Fix: consume view n while views n+1,n+2 are in flight (3 rotating 4-load
// buffers, 8 loads outstanding). Co-resident waves then touch ~1-2 images
// (~2-4MB) at a time -> gather stream becomes L2-resident (~250cyc vs ~900).
// __launch_bounds__(256,4) caps VGPR at 128 -> 16 waves/CU.
// View order + corner order identical to R1 -> bit-identical output.
// ---------------------------------------------------------------------------
#define ISSUE(n, P, q)                                                        \
    P = project_one((n) * B_ + b, gx, gy, gz, R, T, f, ccam, trans, wh);      \
    {                                                                         \
        const uint4* base = (const uint4*)tp + (size_t)((n) * B_ + b) * HW_;  \
        const bool ib = (P.inb != 0.0f);                                      \
        q[0] = base[ib ? P.yi0 * W_ + P.xi0 : 0];                             \
        q[1] = base[ib ? P.yi0 * W_ + P.xi1 : 0];                             \
        q[2] = base[ib ? P.yi1 * W_ + P.xi0 : 0];                             \
        q[3] = base[ib ? P.yi1 * W_ + P.xi1 : 0];                             \
    }

#define CONSUME(P, q)                                                         \
    bndsum += P.inb;                                                          \
    acc_pixel(acc, q[0], P.w00);                                              \
    acc_pixel(acc, q[1], P.w10);                                              \
    acc_pixel(acc, q[2], P.w01);                                              \
    acc_pixel(acc, q[3], P.w11);

__global__ __launch_bounds__(256, 4) void project_kernel_fp8(
    const uint32_t* __restrict__ tp,  // (N,B,H,W,16) fp8
    const float* __restrict__ R, const float* __restrict__ T,
    const float* __restrict__ f, const float* __restrict__ ccam,
    const float* __restrict__ trans, const float* __restrict__ wh,
    const float* __restrict__ gc,
    float* __restrict__ out)
{
    const int bid = blockIdx.x;            // 0..3999
    const int b   = bid & 7;               // XCD affinity: one b per XCD
    const int p   = (bid >> 3) * 256 + (int)threadIdx.x;
    if (p >= NBINS) return;

    const int ixg = p / 1600;
    const int rem = p - ixg * 1600;
    const int iyg = rem / 20;
    const int izg = rem - iyg * 20;
    const float gx = (float)(-4000.0 + ixg * (8000.0 / 79.0)) + gc[b * 3 + 0];
    const float gy = (float)(-4000.0 + iyg * (8000.0 / 79.0)) + gc[b * 3 + 1];
    const float gz = (float)(-1000.0 + izg * (2000.0 / 19.0)) + gc[b * 3 + 2];
    {
        const size_t goff = (size_t)CUBES_ELEMS + ((size_t)b * NBINS + (size_t)p) * 3;
        out[goff + 0] = gx; out[goff + 1] = gy; out[goff + 2] = gz;
    }

    float acc[CP_];
#pragma unroll
    for (int c = 0; c < CP_; ++c) acc[c] = 0.0f;
    float bndsum = 0.0f;

    // 3-buffer rotating pipeline: 8 loads in flight during each consume.
    Proj P0, P1, P2, P3, P4;
    uint4 qA[4], qB[4], qC[4];
    ISSUE(0, P0, qA)
    ISSUE(1, P1, qB)
    ISSUE(2, P2, qC)
    CONSUME(P0, qA)
    ISSUE(3, P3, qA)
    CONSUME(P1, qB)
    ISSUE(4, P4, qB)
    CONSUME(P2, qC)
    CONSUME(P3, qA)
    CONSUME(P4, qB)

    const float inv = 1.0f / (bndsum + 1e-6f);
    const size_t ob = (size_t)b * C_ * NBINS + (size_t)p;
#pragma unroll
    for (int c = 0; c < C_; ++c) {
        float r = acc[c] * inv;
        r = fmaxf(r, 0.0f);   // nan_to_num + clip low
        r = fminf(r, 1.0f);
        out[ob + (size_t)c * NBINS] = r;
    }
}

// ---------------------------------------------------------------------------
// Fallback: direct f32 gather (used only if ws too small). Exact math.
// ---------------------------------------------------------------------------
__device__ __forceinline__ void decode_grid(int p, int b, const float* __restrict__ gc,
                                            float& gx, float& gy, float& gz)
{
    const int ixg = p / 1600;
    const int rem = p - ixg * 1600;
    const int iyg = rem / 20;
    const int izg = rem - iyg * 20;
    gx = (float)(-4000.0 + ixg * (8000.0 / 79.0)) + gc[b * 3 + 0];
    gy = (float)(-4000.0 + iyg * (8000.0 / 79.0)) + gc[b * 3 + 1];
    gz = (float)(-1000.0 + izg * (2000.0 / 19.0)) + gc[b * 3 + 2];
}

__global__ __launch_bounds__(256) void project_kernel_direct(
    const float* __restrict__ hm,
    const float* __restrict__ R, const float* __restrict__ T,
    const float* __restrict__ f, const float* __restrict__ ccam,
    const float* __restrict__ trans, const float* __restrict__ wh,
    const float* __restrict__ gc,
    float* __restrict__ out)
{
    const int p = blockIdx.x * blockDim.x + threadIdx.x;
    const int b = blockIdx.y;
    if (p >= NBINS) return;
    float gx, gy, gz;
    decode_grid(p, b, gc, gx, gy, gz);
    {
        const size_t goff = (size_t)CUBES_ELEMS + ((size_t)b * NBINS + (size_t)p) * 3;
        out[goff + 0] = gx; out[goff + 1] = gy; out[goff + 2] = gz;
    }
    float acc[C_];
#pragma unroll
    for (int c = 0; c < C_; ++c) acc[c] = 0.0f;
    float bndsum = 0.0f;
#pragma unroll
    for (int n = 0; n < N_VIEWS; ++n) {
        const int cb = n * B_ + b;
        Proj cr = project_one(cb, gx, gy, gz, R, T, f, ccam, trans, wh);
        bndsum += cr.inb;
        const bool inb = (cr.inb != 0.0f);
        const int o00 = inb ? cr.yi0 * W_ + cr.xi0 : 0;
        const int o10 = inb ? cr.yi0 * W_ + cr.xi1 : 0;
        const int o01 = inb ? cr.yi1 * W_ + cr.xi0 : 0;
        const int o11 = inb ? cr.yi1 * W_ + cr.xi1 : 0;
        const float* img = hm + (size_t)cb * C_ * HW_;
#pragma unroll
        for (int c = 0; c < C_; ++c) {
            const float* ic = img + (size_t)c * HW_;
            acc[c] += cr.w00 * ic[o00] + cr.w10 * ic[o10]
                    + cr.w01 * ic[o01] + cr.w11 * ic[o11];
        }
    }
    const float inv = 1.0f / (bndsum + 1e-6f);
    const size_t ob = (size_t)b * C_ * NBINS + (size_t)p;
#pragma unroll
    for (int c = 0; c < C_; ++c) {
        float r = acc[c] * inv;
        r = fmaxf(r, 0.0f);
        r = fminf(r, 1.0f);
        out[ob + (size_t)c * NBINS] = r;
    }
}

extern "C" void kernel_launch(void* const* d_in, const int* in_sizes, int n_in,
                              void* d_out, int out_size, void* d_ws, size_t ws_size,
                              hipStream_t stream) {
    const float* hm    = (const float*)d_in[0];
    const float* R     = (const float*)d_in[1];
    const float* T     = (const float*)d_in[2];
    const float* f     = (const float*)d_in[3];
    const float* ccam  = (const float*)d_in[4];
    const float* trans = (const float*)d_in[5];
    const float* wh    = (const float*)d_in[6];
    const float* gc    = (const float*)d_in[7];
    float* out = (float*)d_out;

    const size_t ws_needed = (size_t)NB_ * HW_ * CP_; // 78.6 MB (fp8 bytes)

    if (ws_size >= ws_needed) {
        uint32_t* tp = (uint32_t*)d_ws;
        dim3 tgrid((HW_ / 256) * NB_);        // 19200 flat, b = bid & 7
        transpose_fp8_kernel<<<tgrid, 256, 0, stream>>>(hm, tp);
        dim3 grid((NBINS / 256) * B_);        // 4000 flat, b = bid & 7
        project_kernel_fp8<<<grid, 256, 0, stream>>>(tp, R, T, f, ccam, trans, wh, gc, out);
    } else {
        dim3 grid(NBINS / 256, B_);
        project_kernel_direct<<<grid, 256, 0, stream>>>(hm, R, T, f, ccam, trans, wh, gc, out);
    }
}